// Round 3
// baseline (814.240 us; speedup 1.0000x reference)
//
#include <hip/hip_runtime.h>
#include <stdint.h>

#define F_DIM 321
#define O_DIM 720
#define I_DIM 512
#define B_DIM 32
#define OT_PER_CHUNK 5   // 45 o-tiles of 16 = 9 chunks x 5

typedef __attribute__((ext_vector_type(8))) short short8;   // 8 bf16 = 4 VGPRs
typedef __attribute__((ext_vector_type(4))) float f32x4;
typedef __attribute__((ext_vector_type(4))) uint32_t u32x4;

// Round-to-nearest-even fp32 -> bf16, packed pairwise into a dword.
__device__ __forceinline__ uint32_t rne_pack2(float lo, float hi) {
  uint32_t a = __builtin_bit_cast(uint32_t, lo);
  uint32_t b = __builtin_bit_cast(uint32_t, hi);
  a += 0x7FFFu + ((a >> 16) & 1u);
  b += 0x7FFFu + ((b >> 16) & 1u);
  return (a >> 16) | (b & 0xFFFF0000u);
}

// Kernel 1 (verified R1/R2): xn = x*inv + shift, bf16, A-frag-native layout:
// ws[f][iblk(64)][b(32)] = 16B = 8 consecutive i for that (b,f).
// ~31 MB total traffic; scattered 16-B stores land in L2/L3 (ws hot set
// 10.5 MB) and are re-read by kernel 2 before eviction.
__global__ void __launch_bounds__(256) xn_pack_kernel(
    const float* __restrict__ x, const float* __restrict__ gamma,
    const float* __restrict__ beta, const float* __restrict__ rmean,
    const float* __restrict__ rvar, u32x4* __restrict__ ws) {
  __shared__ float tile[8 * F_DIM];
  const int iblk = blockIdx.x;  // 0..63
  const int b    = blockIdx.y;  // 0..31
  const float* src = x + ((size_t)b * I_DIM + (size_t)iblk * 8) * F_DIM;
  for (int idx = threadIdx.x; idx < 8 * F_DIM; idx += 256)
    tile[idx] = src[idx];
  __syncthreads();
  for (int f = threadIdx.x; f < F_DIM; f += 256) {
    float inv = gamma[f] * rsqrtf(rvar[f] + 1e-5f);
    float sh  = beta[f] - rmean[f] * inv;
    float v[8];
#pragma unroll
    for (int j = 0; j < 8; ++j) v[j] = fmaf(tile[j * F_DIM + f], inv, sh);
    u32x4 pk;
    pk.x = rne_pack2(v[0], v[1]);
    pk.y = rne_pack2(v[2], v[3]);
    pk.z = rne_pack2(v[4], v[5]);
    pk.w = rne_pack2(v[6], v[7]);
    ws[(size_t)f * 2048 + iblk * 32 + b] = pk;
  }
}

// Kernel 2 v3: A-RESIDENT REGISTER STREAMING — no LDS, no barriers.
// Wave = (f-pair, mtile, o-chunk). A-frags for 2 f's live in 128 VGPRs
// (layout = ws granules, verified R1/R2). W streams global->bf16->MFMA
// with a fully unrolled 32-deep load pipeline: no block-wide vmcnt(0)
// drain ever, so outstanding-load depth stays high (R2's limiter).
// The 2 m-tile waves of a block consume the same W stream -> L2 hit,
// DRAM reads W exactly once. G_F=2 -> stores are 8-B f-runs.
__global__ void __launch_bounds__(128, 2) linear_bn_kernel(
    const float* __restrict__ Wt, const float* __restrict__ bias,
    const u32x4* __restrict__ xn, float* __restrict__ out) {
  const int lane  = threadIdx.x & 63;
  const int mtile = threadIdx.x >> 6;   // 2 waves: b-half 0/1
  const int quad  = lane >> 4;
  const int t16   = lane & 15;
  const int f0 = blockIdx.y * 2;
  const int nf = min(2, F_DIM - f0);    // by=160 -> nf=1
  const int chunk = blockIdx.x;         // 0..8

  // Resident A: A[ff][kk] = xn frag, m = mtile*16+t16, k = kk*32+quad*8+j.
  u32x4 A[2][16];
#pragma unroll
  for (int ff = 0; ff < 2; ++ff) {
    if (ff < nf) {
      const u32x4* xf = xn + (size_t)(f0 + ff) * 2048 + mtile * 16 + t16;
#pragma unroll
      for (int kk = 0; kk < 16; ++kk)
        A[ff][kk] = xf[(kk * 4 + quad) * 32];
    }
  }

  for (int t = 0; t < OT_PER_CHUNK; ++t) {   // runtime loop: A stays live
    const int o0 = (chunk * OT_PER_CHUNK + t) * 16;
    const int oC = o0 + t16;                 // 45*16=720 exact, no guard
    f32x4 acc[2];
#pragma unroll
    for (int ff = 0; ff < 2; ++ff) {
      float bv = (ff < nf) ? bias[(size_t)(f0 + ff) * O_DIM + oC] : 0.0f;
      acc[ff] = (f32x4){bv, bv, bv, bv};
    }
#pragma unroll
    for (int kk = 0; kk < 16; ++kk) {
#pragma unroll
      for (int ff = 0; ff < 2; ++ff) {       // 2 independent acc chains
        if (ff < nf) {
          // B[k=quad*8+j][n=t16] <- W[f][oC][kk*32+quad*8 ..+8], fp32->bf16
          const float* pb =
              Wt + ((size_t)(f0 + ff) * O_DIM + oC) * I_DIM + kk * 32 + quad * 8;
          f32x4 w0 = *(const f32x4*)pb;
          f32x4 w1 = *(const f32x4*)(pb + 4);
          u32x4 bu;
          bu.x = rne_pack2(w0.x, w0.y);
          bu.y = rne_pack2(w0.z, w0.w);
          bu.z = rne_pack2(w1.x, w1.y);
          bu.w = rne_pack2(w1.z, w1.w);
          acc[ff] = __builtin_amdgcn_mfma_f32_16x16x32_bf16(
              __builtin_bit_cast(short8, A[ff][kk]),
              __builtin_bit_cast(short8, bu), acc[ff], 0, 0, 0);
        }
      }
    }
    // C/D: col=t16 (o), row=quad*4+r (b within mtile). f-pair -> 8-B runs.
#pragma unroll
    for (int r = 0; r < 4; ++r) {
      const int brow = mtile * 16 + quad * 4 + r;
      float* po = out + ((size_t)brow * O_DIM + oC) * F_DIM + f0;
      po[0] = acc[0][r];
      if (nf == 2) po[1] = acc[1][r];
    }
  }
}

extern "C" void kernel_launch(void* const* d_in, const int* in_sizes, int n_in,
                              void* d_out, int out_size, void* d_ws, size_t ws_size,
                              hipStream_t stream) {
  const float* x     = (const float*)d_in[0];
  const float* W     = (const float*)d_in[1];
  const float* b     = (const float*)d_in[2];
  const float* gamma = (const float*)d_in[3];
  const float* beta  = (const float*)d_in[4];
  const float* rmean = (const float*)d_in[5];
  const float* rvar  = (const float*)d_in[6];
  u32x4* ws = (u32x4*)d_ws;  // 321*2048*16 B = 10.5 MB << ws_size

  xn_pack_kernel<<<dim3(64, 32), 256, 0, stream>>>(x, gamma, beta, rmean, rvar, ws);
  // grid: 9 o-chunks x 161 f-pairs, 128-thread blocks (2 m-tile waves)
  linear_bn_kernel<<<dim3(9, 161), 128, 0, stream>>>(W, b, ws, (float*)d_out);
}